// Round 22
// baseline (169.599 us; speedup 1.0000x reference)
//
#include <hip/hip_runtime.h>
#include <hip/hip_bf16.h>

#define T 2048
#define HID 2048
#define NH 16
#define NKH 4
#define HD 128
#define GSZ 128

typedef __attribute__((ext_vector_type(8))) short short8;
typedef __attribute__((ext_vector_type(4))) float f32x4;

#define GLOAD16(gp, lp) __builtin_amdgcn_global_load_lds( \
    (const __attribute__((address_space(1))) void*)(gp), \
    (__attribute__((address_space(3))) void*)(lp), 16, 0, 0)

__device__ inline short f2b(float f) {
    unsigned int u = __float_as_uint(f);
    unsigned int r = (u + 0x7fffu + ((u >> 16) & 1u)) >> 16;
    return (short)r;
}
__device__ inline float b2f(unsigned short u) {
    return __uint_as_float((unsigned int)u << 16);
}

// ---------------- dequant helper: 8 int4 -> bf16 W^T row chunk ----------------
__device__ inline void dq8(const int* __restrict__ qw, const float* __restrict__ sc,
                           const int* __restrict__ qz, short* __restrict__ Wt,
                           int K, int N, int tid) {
    int K8 = K >> 3;
    int n = tid / K8;
    int k8 = tid - n * K8;
    int q32 = qw[k8 * N + n];
    int g = (k8 << 3) / GSZ;
    float scale = sc[g * N + n];
    int z = (qz[g * (N >> 3) + (n >> 3)] >> ((n & 7) * 4)) & 15;
    float zf = (float)(z + 1);
    short8 out;
#pragma unroll
    for (int kk = 0; kk < 8; kk++) {
        int q = (q32 >> (kk * 4)) & 15;
        out[kk] = f2b(scale * ((float)q - zf));
    }
    *reinterpret_cast<short8*>(&Wt[(size_t)n * K + (k8 << 3)]) = out;
}

// ------- prep: fused dequant x4 + x cast (one launch) -------
__global__ __launch_bounds__(256) void prep_kernel(
    const int* __restrict__ qw_q, const float* __restrict__ sc_q, const int* __restrict__ qz_q,
    const int* __restrict__ qw_k, const float* __restrict__ sc_k, const int* __restrict__ qz_k,
    const int* __restrict__ qw_v, const float* __restrict__ sc_v, const int* __restrict__ qz_v,
    const int* __restrict__ qw_o, const float* __restrict__ sc_o, const int* __restrict__ qz_o,
    const float* __restrict__ x, short* __restrict__ Wqkv, short* __restrict__ Wo,
    short* __restrict__ xb) {
    int tid = blockIdx.x * 256 + threadIdx.x;
    if (tid < 524288) { dq8(qw_q, sc_q, qz_q, Wqkv, 2048, 2048, tid); return; }
    tid -= 524288;
    if (tid < 131072) { dq8(qw_k, sc_k, qz_k, Wqkv + 2048 * 2048, 2048, 512, tid); return; }
    tid -= 131072;
    if (tid < 131072) { dq8(qw_v, sc_v, qz_v, Wqkv + 2560 * 2048, 2048, 512, tid); return; }
    tid -= 131072;
    if (tid < 524288) { dq8(qw_o, sc_o, qz_o, Wo, 2048, 2048, tid); return; }
    tid -= 524288;
    const float4* xp = reinterpret_cast<const float4*>(x) + (size_t)tid * 2;
    float4 a = xp[0], b = xp[1];
    short8 o;
    o[0] = f2b(a.x); o[1] = f2b(a.y); o[2] = f2b(a.z); o[3] = f2b(a.w);
    o[4] = f2b(b.x); o[5] = f2b(b.y); o[6] = f2b(b.z); o[7] = f2b(b.w);
    reinterpret_cast<short8*>(xb)[tid] = o;
}

// -------- GEMM: C[M,N] = A[M,K]bf16 * Bt[N,K]bf16^T  (64x64 tile, dbuf) ------
// BM=64 doubles block count vs 128x64 (QKV 1536 = ~6/CU, O-proj 1024 = 4/CU;
// LDS 32KB -> 5 resident) -- the latency-bound 2-barrier loop gets 1.7-2x the
// waves/CU. XCD-aware tile assignment (bijective: gridDim.x % 8 == 0).
#define BM 64
#define BN 64
#define BK 64

template <int BF16OUT>
__global__ __launch_bounds__(256) void gemm_bt(
    const short* __restrict__ A, const short* __restrict__ Bt,
    float* __restrict__ C, int M, int N, int K) {
    __shared__ short As[2][BM * BK];   // 8 chunks of 512 elems per buf
    __shared__ short Bs[2][BN * BK];   // 8 chunks per buf
    const int t = threadIdx.x;
    const int lane = t & 63;
    const int w = t >> 6;
    const int nbx = gridDim.x;
    const int per = nbx >> 3;                    // bn columns per XCD
    const int flat = blockIdx.y * nbx + blockIdx.x;   // dispatch order (x fastest)
    const int xcd = flat & 7;
    const int i = flat >> 3;
    const int bn = (xcd * per + (i % per)) * BN;
    const int bm = (i / per) * BM;
    const int wm = (w >> 1) * 32;   // 0 / 32
    const int wn = (w & 1) * 32;    // 0 / 32
    const int lr = lane & 15;
    const int lk = (lane >> 4) * 8;
    const int srow = lane >> 3;
    const int scol = ((lane & 7) ^ srow) * 8;
    f32x4 acc[2][2] = {};

#pragma unroll
    for (int i2 = 0; i2 < 2; i2++) {
        int c = w * 2 + i2;
        GLOAD16(&A[(size_t)(bm + c * 8 + srow) * K + scol], &As[0][c * 512]);
        GLOAD16(&Bt[(size_t)(bn + c * 8 + srow) * K + scol], &Bs[0][c * 512]);
    }
    __syncthreads();

    int cur = 0;
    for (int k0 = 0; k0 < K; k0 += BK) {
        if (k0 + BK < K) {
            const int kn = k0 + BK;
#pragma unroll
            for (int i2 = 0; i2 < 2; i2++) {
                int c = w * 2 + i2;
                GLOAD16(&A[(size_t)(bm + c * 8 + srow) * K + kn + scol],
                        &As[cur ^ 1][c * 512]);
                GLOAD16(&Bt[(size_t)(bn + c * 8 + srow) * K + kn + scol],
                        &Bs[cur ^ 1][c * 512]);
            }
        }
        __builtin_amdgcn_s_setprio(1);
#pragma unroll
        for (int kc = 0; kc < 2; kc++) {
            short8 af[2], bf[2];
#pragma unroll
            for (int m = 0; m < 2; m++) {
                int r = wm + m * 16 + lr;
                af[m] = *reinterpret_cast<const short8*>(
                    &As[cur][r * BK + ((kc * 32 + lk) ^ ((r & 7) * 8))]);
            }
#pragma unroll
            for (int n = 0; n < 2; n++) {
                int r = wn + n * 16 + lr;
                bf[n] = *reinterpret_cast<const short8*>(
                    &Bs[cur][r * BK + ((kc * 32 + lk) ^ ((r & 7) * 8))]);
            }
#pragma unroll
            for (int m = 0; m < 2; m++)
#pragma unroll
                for (int n = 0; n < 2; n++)
                    acc[m][n] = __builtin_amdgcn_mfma_f32_16x16x32_bf16(
                        af[m], bf[n], acc[m][n], 0, 0, 0);
        }
        __builtin_amdgcn_s_setprio(0);
        __syncthreads();
        cur ^= 1;
    }
    const int rowb = bm + wm + (lane >> 4) * 4;
    const int colb = bn + wn + lr;
    if constexpr (BF16OUT) {
        unsigned short* Cb = reinterpret_cast<unsigned short*>(C);
#pragma unroll
        for (int m = 0; m < 2; m++)
#pragma unroll
            for (int n = 0; n < 2; n++)
#pragma unroll
                for (int rr = 0; rr < 4; rr++)
                    Cb[(size_t)(rowb + m * 16 + rr) * N + colb + n * 16] =
                        (unsigned short)f2b(acc[m][n][rr]);
    } else {
#pragma unroll
        for (int m = 0; m < 2; m++)
#pragma unroll
            for (int n = 0; n < 2; n++)
#pragma unroll
                for (int rr = 0; rr < 4; rr++)
                    C[(size_t)(rowb + m * 16 + rr) * N + colb + n * 16] = acc[m][n][rr];
    }
}

// ------- fused rmsnorm+rope (y<20, 2 tokens/block) & V transpose (y=20) -------
__global__ __launch_bounds__(256) void nrv_kernel(
    const unsigned short* __restrict__ qkvb, const float* __restrict__ qw,
    const float* __restrict__ kw, const int* __restrict__ pos,
    short* __restrict__ Qb, short* __restrict__ Kb, short* __restrict__ Vt) {
    const int by = blockIdx.y;
    const int bx = blockIdx.x;
    const int tid = threadIdx.x;
    if (by < 20) {
        __shared__ float red[4];
        __shared__ float vals[2][HD];
        const int p = tid >> 7;
        const int d = tid & 127;
        const int tt = bx * 2 + p;
        const int hh = by;
        bool isq = hh < NH;
        int h = isq ? hh : hh - NH;
        int off = isq ? h * HD : HID + h * HD;
        float x = b2f(qkvb[(size_t)tt * 3072 + off + d]);
        float ss = x * x;
#pragma unroll
        for (int mask = 1; mask < 64; mask <<= 1) ss += __shfl_xor(ss, mask, 64);
        if ((tid & 63) == 0) red[tid >> 6] = ss;
        __syncthreads();
        float tot = red[p * 2] + red[p * 2 + 1];
        float r = rsqrtf(tot * (1.0f / HD) + 1e-6f);
        float wv = isq ? qw[d] : kw[d];
        float xn = x * r * wv;
        vals[p][d] = xn;
        __syncthreads();
        int pp = pos[tt];
        int i = d & 63;
        float inv = exp2f(-(float)i * (13.287712379549449f / 64.0f));
        float ang = (float)pp * inv;
        float c, s;
        sincosf(ang, &s, &c);
        float other = vals[p][d ^ 64];
        float out = (d < 64) ? (xn * c - other * s) : (xn * c + other * s);
        if (isq) Qb[(size_t)tt * HID + h * HD + d] = f2b(out);
        else     Kb[(size_t)(h * T + tt) * HD + d] = f2b(out);
    } else {
        __shared__ short tile[32][33];
        const int kvh = bx & 3;
        const int d0 = ((bx >> 2) & 3) * 32;
        const int t0 = (bx >> 4) * 32;
        const int tx = tid & 31;
        const int ty = tid >> 5;
#pragma unroll
        for (int i = 0; i < 32; i += 8)
            tile[ty + i][tx] = (short)qkvb[(size_t)(t0 + ty + i) * 3072 + 2560 + kvh * HD + d0 + tx];
        __syncthreads();
#pragma unroll
        for (int i = 0; i < 32; i += 8)
            Vt[(size_t)(kvh * HD + d0 + ty + i) * T + t0 + tx] = tile[tx][ty + i];
    }
}

// -------- flash attention (best measured config: R13/R19, PLD=40) --------
// split-K, FIXED-MAX softmax, QB=128 / 8 waves of 16x16 MFMA.
// K LDS [32][128] chunk16-XOR swizzled; V LDS [128][32] chunk4-XOR swizzled.
// U: packed u32, permuted cols, NT full-line stores.
#define QB 128
#define KVB 32
#define NSPLIT 4
#define PLD 40

__global__ __launch_bounds__(512) void attn_split_kernel(
    const short* __restrict__ Qb, const short* __restrict__ Kb,
    const short* __restrict__ Vt, unsigned int* __restrict__ U32,
    float2* __restrict__ stats) {
    __shared__ short Ks[2][KVB * HD];   // [32][128], chunk-swizzled
    __shared__ short Vs[2][HD * KVB];   // [128][32], chunk-swizzled
    __shared__ short P[8][16 * PLD];
    const int t = threadIdx.x;
    const int lane = t & 63;
    const int w = t >> 6;               // 0..7
    const int h = blockIdx.y;
    const int sp = blockIdx.z;
    const int kvh = h >> 2;
    int bx = blockIdx.x;
    const int qt = (bx & 1) ? ((int)gridDim.x - 1 - (bx >> 1)) : (bx >> 1);
    const int qb0 = qt * QB;
    const int lr = lane & 15;
    const int g = lane >> 4;
    const int lk = g * 8;
    const int rowb = qb0 + w * 16 + g * 4;
    const int len = qt + 1;             // equal non-empty splits (nt = 4*(qt+1))
    const int jt0 = sp * len;
    const int jt1 = jt0 + len;

    f32x4 oacc[8] = {};
    f32x4 lacc = {};                           // row-sums via ones-MFMA
    const float scale = 0.08838834764831845f;  // 1/sqrt(128)
    short8 kOnes;
#pragma unroll
    for (int kk = 0; kk < 8; kk++) kOnes[kk] = (short)0x3F80;  // bf16 1.0

    short8 qf[4];
    {
        const short* qp = Qb + (size_t)(qb0 + w * 16 + lr) * HID + h * HD + lk;
#pragma unroll
        for (int kk = 0; kk < 4; kk++)
            qf[kk] = *reinterpret_cast<const short8*>(qp + kk * 32);
    }
    const short* kgb = Kb + (size_t)(kvh * T) * HD;
    const short* vgb = Vt + (size_t)(kvh * HD) * T;
    const int kr4 = lane >> 4;            // K stage: row within 4-row chunk
    const int vr16 = lane >> 2;           // V stage: d-row within 16-row chunk
    const int r7 = ((w & 1) << 2) | kr4;  // (w*4+kr4) & 7
    const int kcol = ((lane & 15) ^ r7) * 8;               // K pre-swizzled col
    const int vcol = ((lane & 3) ^ ((lane >> 2) & 3)) * 8; // V pre-swizzled col

    // prologue: stage tile jt0 into buf 0 (wave w stages chunk w of K and V)
    {
        const int key0 = jt0 * KVB;
        GLOAD16(kgb + (size_t)(key0 + w * 4 + kr4) * HD + kcol, &Ks[0][w * 512]);
        GLOAD16(vgb + (size_t)(w * 16 + vr16) * T + key0 + vcol, &Vs[0][w * 512]);
    }
    __syncthreads();

    int cur = 0;
    for (int j = jt0; j < jt1; j++) {
        const int key0 = j * KVB;
        if (j + 1 < jt1) {
            const int nk0 = key0 + KVB;
            GLOAD16(kgb + (size_t)(nk0 + w * 4 + kr4) * HD + kcol, &Ks[cur ^ 1][w * 512]);
            GLOAD16(vgb + (size_t)(w * 16 + vr16) * T + nk0 + vcol, &Vs[cur ^ 1][w * 512]);
        }
        // ---- QK^T: S[16q][32k] per wave (swizzled K reads) ----
        f32x4 sv[2] = {};
        __builtin_amdgcn_s_setprio(1);
#pragma unroll
        for (int kt = 0; kt < 2; kt++) {
            int r = kt * 16 + lr;
            int rx = (r & 7) * 8;
#pragma unroll
            for (int kk = 0; kk < 4; kk++) {
                short8 b = *reinterpret_cast<const short8*>(
                    &Ks[cur][r * HD + ((kk * 32 + lk) ^ rx)]);
                sv[kt] = __builtin_amdgcn_mfma_f32_16x16x32_bf16(qf[kk], b, sv[kt], 0, 0, 0);
            }
        }
        __builtin_amdgcn_s_setprio(0);
        // ---- fixed-max softmax: p = exp(s*scale - 12), mask -> exp(-inf)=0 ----
        {
            int prow = g * 4;
#pragma unroll
            for (int rr = 0; rr < 4; rr++) {
                int row = rowb + rr;
                float v0 = (key0 + lr <= row) ? fmaf(sv[0][rr], scale, -12.f) : -1e30f;
                float v1 = (key0 + 16 + lr <= row) ? fmaf(sv[1][rr], scale, -12.f) : -1e30f;
                float p0 = __expf(v0);
                float p1 = __expf(v1);
                P[w][(prow + rr) * PLD + lr] = (short)(__float_as_uint(p0) >> 16);
                P[w][(prow + rr) * PLD + 16 + lr] = (short)(__float_as_uint(p1) >> 16);
            }
        }
        // P is wave-private: compiler lgkmcnt ordering suffices, no barrier.
        short8 pa = *reinterpret_cast<const short8*>(&P[w][lr * PLD + lk]);
        // ---- PV: O[16q][128d] += P[16][32] * V[32][128]; l += P.1 ----
        __builtin_amdgcn_s_setprio(1);
        lacc = __builtin_amdgcn_mfma_f32_16x16x32_bf16(pa, kOnes, lacc, 0, 0, 0);
#pragma unroll
        for (int c = 0; c < 8; c++) {
            int r = c * 16 + lr;
            short8 bv = *reinterpret_cast<const short8*>(
                &Vs[cur][r * KVB + ((g ^ (r & 3)) * 8)]);
            oacc[c] = __builtin_amdgcn_mfma_f32_16x16x32_bf16(pa, bv, oacc[c], 0, 0, 0);
        }
        __builtin_amdgcn_s_setprio(0);
        __syncthreads();   // drains staging vmcnt + protects dbuf reuse
        cur ^= 1;
    }
    // ---- emit U: packed u32, permuted cols, NT, full 64B lines ----
    unsigned int* ub = U32 + ((size_t)(sp * NH + h) * T + rowb) * (HD / 2);
#pragma unroll
    for (int cp = 0; cp < 4; cp++)
#pragma unroll
        for (int rr = 0; rr < 4; rr++) {
            unsigned int w32 = (unsigned int)(unsigned short)f2b(oacc[2 * cp][rr]) |
                               ((unsigned int)(unsigned short)f2b(oacc[2 * cp + 1][rr]) << 16);
            __builtin_nontemporal_store(w32, &ub[rr * (HD / 2) + cp * 16 + lr]);
        }
    // ---- stats ----
    if (lr == 0) {
#pragma unroll
        for (int rr = 0; rr < 4; rr++)
            stats[(size_t)(sp * NH + h) * T + rowb + rr] = make_float2(12.f, lacc[rr]);
    }
}

// ------- combine: equal-weight merge of 4 splits (permuted u32 U) -> Ob -------
__global__ __launch_bounds__(256) void combine_kernel(
    const unsigned int* __restrict__ U32, const float2* __restrict__ stats,
    short* __restrict__ Ob) {
    const int w = threadIdx.x >> 6;
    const int lane = threadIdx.x & 63;
    const int rid = blockIdx.x * 4 + w;      // h*T + t
    const int h = rid >> 11;
    const int tt = rid & (T - 1);
    float l[NSPLIT];
    float den = 0.f;
#pragma unroll
    for (int sp = 0; sp < NSPLIT; sp++) {
        l[sp] = stats[(size_t)sp * NH * T + rid].y;
        den += l[sp];
    }
    float inv = 1.0f / den;
    float o0 = 0.f, o1 = 0.f;
#pragma unroll
    for (int sp = 0; sp < NSPLIT; sp++) {
        if (l[sp] > 0.f) {   // wave-uniform branch
            unsigned int u = __builtin_nontemporal_load(
                &U32[((size_t)(sp * NH + h) * T + tt) * (HD / 2) + lane]);
            o0 += b2f((unsigned short)(u & 0xffff));
            o1 += b2f((unsigned short)(u >> 16));
        }
    }
    o0 *= inv; o1 *= inv;
    const int c0 = 32 * (lane >> 4) + (lane & 15);
    short* obp = Ob + (size_t)tt * HID + h * HD;
    obp[c0] = f2b(o0);
    obp[c0 + 16] = f2b(o1);
}

extern "C" void kernel_launch(void* const* d_in, const int* in_sizes, int n_in,
                              void* d_out, int out_size, void* d_ws, size_t ws_size,
                              hipStream_t stream) {
    const float* x = (const float*)d_in[0];
    const int* positions = (const int*)d_in[1];
    const int* qw_q = (const int*)d_in[2];
    const float* sc_q = (const float*)d_in[3];
    const int* qz_q = (const int*)d_in[4];
    const int* qw_k = (const int*)d_in[5];
    const float* sc_k = (const float*)d_in[6];
    const int* qz_k = (const int*)d_in[7];
    const int* qw_v = (const int*)d_in[8];
    const float* sc_v = (const float*)d_in[9];
    const int* qz_v = (const int*)d_in[10];
    const int* qw_o = (const int*)d_in[11];
    const float* sc_o = (const float*)d_in[12];
    const int* qz_o = (const int*)d_in[13];
    const float* qnw = (const float*)d_in[14];
    const float* knw = (const float*)d_in[15];
    float* out = (float*)d_out;

    char* ws = (char*)d_ws;
    short* Wqkv = (short*)(ws);                  // [3072][2048] bf16 (dead after QKV GEMM)
    short* Wo   = (short*)(ws + 12582912);       // [2048][2048] bf16 (live till end)
    short* xb   = (short*)(ws + 20971520);       // [2048][2048] bf16 (dead after QKV GEMM)
    unsigned short* qkvb = (unsigned short*)(ws + 29360128); // [2048][3072] bf16
    short* Qb   = (short*)(ws + 54525952);       // [2048][2048] bf16
    short* Kb   = (short*)(ws + 62914560);       // [4][2048][128] bf16
    short* Vt   = (short*)(ws + 65011712);       // [4][128][2048] bf16
    short* Ob   = (short*)(ws + 67108864);       // [2048][2048] bf16
    float2* stats   = (float2*)(ws);             // [4][16][2048] float2 (over Wqkv)
    unsigned int* U = (unsigned int*)(ws + 20971520); // [4][16][2048][64] u32 = 32 MB

    prep_kernel<<<7168, 256, 0, stream>>>(qw_q, sc_q, qz_q, qw_k, sc_k, qz_k,
                                          qw_v, sc_v, qz_v, qw_o, sc_o, qz_o,
                                          x, Wqkv, Wo, xb);

    dim3 g1(3072 / BN, 2048 / BM);               // 48 x 32 = 1536 blocks
    gemm_bt<1><<<g1, 256, 0, stream>>>(xb, Wqkv, (float*)qkvb, 2048, 3072, 2048);

    dim3 g2(1024, 21);
    nrv_kernel<<<g2, 256, 0, stream>>>(qkvb, qnw, knw, positions, Qb, Kb, Vt);

    dim3 g4(T / QB, NH, NSPLIT);                 // 16 x 16 x 4 = 1024 blocks x 512 thr
    attn_split_kernel<<<g4, 512, 0, stream>>>(Qb, Kb, Vt, U, stats);

    combine_kernel<<<(T * NH) / 4, 256, 0, stream>>>(U, stats, Ob);

    dim3 g5(2048 / BN, 2048 / BM);               // 32 x 32 = 1024 blocks
    gemm_bt<0><<<g5, 256, 0, stream>>>(Ob, Wo, out, 2048, 2048, 2048);
}

// Round 23
// 157.646 us; speedup vs baseline: 1.0758x; 1.0758x over previous
//
#include <hip/hip_runtime.h>
#include <hip/hip_bf16.h>

#define T 2048
#define HID 2048
#define NH 16
#define NKH 4
#define HD 128
#define GSZ 128

typedef __attribute__((ext_vector_type(8))) short short8;
typedef __attribute__((ext_vector_type(4))) float f32x4;

#define GLOAD16(gp, lp) __builtin_amdgcn_global_load_lds( \
    (const __attribute__((address_space(1))) void*)(gp), \
    (__attribute__((address_space(3))) void*)(lp), 16, 0, 0)

__device__ inline short f2b(float f) {
    unsigned int u = __float_as_uint(f);
    unsigned int r = (u + 0x7fffu + ((u >> 16) & 1u)) >> 16;
    return (short)r;
}
__device__ inline float b2f(unsigned short u) {
    return __uint_as_float((unsigned int)u << 16);
}

// ---------------- dequant helper: 8 int4 -> bf16 W^T row chunk ----------------
__device__ inline void dq8(const int* __restrict__ qw, const float* __restrict__ sc,
                           const int* __restrict__ qz, short* __restrict__ Wt,
                           int K, int N, int tid) {
    int K8 = K >> 3;
    int n = tid / K8;
    int k8 = tid - n * K8;
    int q32 = qw[k8 * N + n];
    int g = (k8 << 3) / GSZ;
    float scale = sc[g * N + n];
    int z = (qz[g * (N >> 3) + (n >> 3)] >> ((n & 7) * 4)) & 15;
    float zf = (float)(z + 1);
    short8 out;
#pragma unroll
    for (int kk = 0; kk < 8; kk++) {
        int q = (q32 >> (kk * 4)) & 15;
        out[kk] = f2b(scale * ((float)q - zf));
    }
    *reinterpret_cast<short8*>(&Wt[(size_t)n * K + (k8 << 3)]) = out;
}

// ------- prep: fused dequant x4 + x cast (one launch) -------
__global__ __launch_bounds__(256) void prep_kernel(
    const int* __restrict__ qw_q, const float* __restrict__ sc_q, const int* __restrict__ qz_q,
    const int* __restrict__ qw_k, const float* __restrict__ sc_k, const int* __restrict__ qz_k,
    const int* __restrict__ qw_v, const float* __restrict__ sc_v, const int* __restrict__ qz_v,
    const int* __restrict__ qw_o, const float* __restrict__ sc_o, const int* __restrict__ qz_o,
    const float* __restrict__ x, short* __restrict__ Wqkv, short* __restrict__ Wo,
    short* __restrict__ xb) {
    int tid = blockIdx.x * 256 + threadIdx.x;
    if (tid < 524288) { dq8(qw_q, sc_q, qz_q, Wqkv, 2048, 2048, tid); return; }
    tid -= 524288;
    if (tid < 131072) { dq8(qw_k, sc_k, qz_k, Wqkv + 2048 * 2048, 2048, 512, tid); return; }
    tid -= 131072;
    if (tid < 131072) { dq8(qw_v, sc_v, qz_v, Wqkv + 2560 * 2048, 2048, 512, tid); return; }
    tid -= 131072;
    if (tid < 524288) { dq8(qw_o, sc_o, qz_o, Wo, 2048, 2048, tid); return; }
    tid -= 524288;
    const float4* xp = reinterpret_cast<const float4*>(x) + (size_t)tid * 2;
    float4 a = xp[0], b = xp[1];
    short8 o;
    o[0] = f2b(a.x); o[1] = f2b(a.y); o[2] = f2b(a.z); o[3] = f2b(a.w);
    o[4] = f2b(b.x); o[5] = f2b(b.y); o[6] = f2b(b.z); o[7] = f2b(b.w);
    reinterpret_cast<short8*>(xb)[tid] = o;
}

// -------- GEMM: C[M,N] = A[M,K]bf16 * Bt[N,K]bf16^T  (128x64 tile, dbuf) -----
// XCD-aware tile assignment (T1, bijective: gridDim.x % 8 == 0).
#define BM 128
#define BN 64
#define BK 64

template <int BF16OUT>
__global__ __launch_bounds__(256) void gemm_bt(
    const short* __restrict__ A, const short* __restrict__ Bt,
    float* __restrict__ C, int M, int N, int K) {
    __shared__ short As[2][BM * BK];
    __shared__ short Bs[2][BN * BK];
    const int t = threadIdx.x;
    const int lane = t & 63;
    const int w = t >> 6;
    const int nbx = gridDim.x;
    const int per = nbx >> 3;                    // bn columns per XCD
    const int flat = blockIdx.y * nbx + blockIdx.x;   // dispatch order (x fastest)
    const int xcd = flat & 7;
    const int i = flat >> 3;
    const int bn = (xcd * per + (i % per)) * BN;
    const int bm = (i / per) * BM;
    const int wm = (w >> 1) * 64;
    const int wn = (w & 1) * 32;
    const int lr = lane & 15;
    const int lk = (lane >> 4) * 8;
    const int srow = lane >> 3;
    const int scol = ((lane & 7) ^ srow) * 8;
    f32x4 acc[4][2] = {};

#pragma unroll
    for (int i2 = 0; i2 < 4; i2++) {
        int c = w * 4 + i2;
        GLOAD16(&A[(size_t)(bm + c * 8 + srow) * K + scol], &As[0][c * 512]);
    }
#pragma unroll
    for (int i2 = 0; i2 < 2; i2++) {
        int c = w * 2 + i2;
        GLOAD16(&Bt[(size_t)(bn + c * 8 + srow) * K + scol], &Bs[0][c * 512]);
    }
    __syncthreads();

    int cur = 0;
    for (int k0 = 0; k0 < K; k0 += BK) {
        if (k0 + BK < K) {
            const int kn = k0 + BK;
#pragma unroll
            for (int i2 = 0; i2 < 4; i2++) {
                int c = w * 4 + i2;
                GLOAD16(&A[(size_t)(bm + c * 8 + srow) * K + kn + scol],
                        &As[cur ^ 1][c * 512]);
            }
#pragma unroll
            for (int i2 = 0; i2 < 2; i2++) {
                int c = w * 2 + i2;
                GLOAD16(&Bt[(size_t)(bn + c * 8 + srow) * K + kn + scol],
                        &Bs[cur ^ 1][c * 512]);
            }
        }
        __builtin_amdgcn_s_setprio(1);
#pragma unroll
        for (int kc = 0; kc < 2; kc++) {
            short8 af[4], bf[2];
#pragma unroll
            for (int m = 0; m < 4; m++) {
                int r = wm + m * 16 + lr;
                af[m] = *reinterpret_cast<const short8*>(
                    &As[cur][r * BK + ((kc * 32 + lk) ^ ((r & 7) * 8))]);
            }
#pragma unroll
            for (int n = 0; n < 2; n++) {
                int r = wn + n * 16 + lr;
                bf[n] = *reinterpret_cast<const short8*>(
                    &Bs[cur][r * BK + ((kc * 32 + lk) ^ ((r & 7) * 8))]);
            }
#pragma unroll
            for (int m = 0; m < 4; m++)
#pragma unroll
                for (int n = 0; n < 2; n++)
                    acc[m][n] = __builtin_amdgcn_mfma_f32_16x16x32_bf16(
                        af[m], bf[n], acc[m][n], 0, 0, 0);
        }
        __builtin_amdgcn_s_setprio(0);
        __syncthreads();
        cur ^= 1;
    }
    const int rowb = bm + wm + (lane >> 4) * 4;
    const int colb = bn + wn + lr;
    if constexpr (BF16OUT) {
        unsigned short* Cb = reinterpret_cast<unsigned short*>(C);
#pragma unroll
        for (int m = 0; m < 4; m++)
#pragma unroll
            for (int n = 0; n < 2; n++)
#pragma unroll
                for (int rr = 0; rr < 4; rr++)
                    Cb[(size_t)(rowb + m * 16 + rr) * N + colb + n * 16] =
                        (unsigned short)f2b(acc[m][n][rr]);
    } else {
#pragma unroll
        for (int m = 0; m < 4; m++)
#pragma unroll
            for (int n = 0; n < 2; n++)
#pragma unroll
                for (int rr = 0; rr < 4; rr++)
                    C[(size_t)(rowb + m * 16 + rr) * N + colb + n * 16] = acc[m][n][rr];
    }
}

// ------- fused rmsnorm+rope (y<20, 2 tokens/block) & V transpose (y=20) -------
__global__ __launch_bounds__(256) void nrv_kernel(
    const unsigned short* __restrict__ qkvb, const float* __restrict__ qw,
    const float* __restrict__ kw, const int* __restrict__ pos,
    short* __restrict__ Qb, short* __restrict__ Kb, short* __restrict__ Vt) {
    const int by = blockIdx.y;
    const int bx = blockIdx.x;
    const int tid = threadIdx.x;
    if (by < 20) {
        __shared__ float red[4];
        __shared__ float vals[2][HD];
        const int p = tid >> 7;
        const int d = tid & 127;
        const int tt = bx * 2 + p;
        const int hh = by;
        bool isq = hh < NH;
        int h = isq ? hh : hh - NH;
        int off = isq ? h * HD : HID + h * HD;
        float x = b2f(qkvb[(size_t)tt * 3072 + off + d]);
        float ss = x * x;
#pragma unroll
        for (int mask = 1; mask < 64; mask <<= 1) ss += __shfl_xor(ss, mask, 64);
        if ((tid & 63) == 0) red[tid >> 6] = ss;
        __syncthreads();
        float tot = red[p * 2] + red[p * 2 + 1];
        float r = rsqrtf(tot * (1.0f / HD) + 1e-6f);
        float wv = isq ? qw[d] : kw[d];
        float xn = x * r * wv;
        vals[p][d] = xn;
        __syncthreads();
        int pp = pos[tt];
        int i = d & 63;
        float inv = exp2f(-(float)i * (13.287712379549449f / 64.0f));
        float ang = (float)pp * inv;
        float c, s;
        sincosf(ang, &s, &c);
        float other = vals[p][d ^ 64];
        float out = (d < 64) ? (xn * c - other * s) : (xn * c + other * s);
        if (isq) Qb[(size_t)tt * HID + h * HD + d] = f2b(out);
        else     Kb[(size_t)(h * T + tt) * HD + d] = f2b(out);
    } else {
        __shared__ short tile[32][33];
        const int kvh = bx & 3;
        const int d0 = ((bx >> 2) & 3) * 32;
        const int t0 = (bx >> 4) * 32;
        const int tx = tid & 31;
        const int ty = tid >> 5;
#pragma unroll
        for (int i = 0; i < 32; i += 8)
            tile[ty + i][tx] = (short)qkvb[(size_t)(t0 + ty + i) * 3072 + 2560 + kvh * HD + d0 + tx];
        __syncthreads();
#pragma unroll
        for (int i = 0; i < 32; i += 8)
            Vt[(size_t)(kvh * HD + d0 + ty + i) * T + t0 + tx] = tile[tx][ty + i];
    }
}

// -------- flash attention (best measured config: R13/R19, PLD=40) --------
// split-K, FIXED-MAX softmax, QB=128 / 8 waves of 16x16 MFMA.
// K LDS [32][128] chunk16-XOR swizzled; V LDS [128][32] chunk4-XOR swizzled.
// U: packed u32, permuted cols, NT full-line stores.
#define QB 128
#define KVB 32
#define NSPLIT 4
#define PLD 40

__global__ __launch_bounds__(512) void attn_split_kernel(
    const short* __restrict__ Qb, const short* __restrict__ Kb,
    const short* __restrict__ Vt, unsigned int* __restrict__ U32,
    float2* __restrict__ stats) {
    __shared__ short Ks[2][KVB * HD];   // [32][128], chunk-swizzled
    __shared__ short Vs[2][HD * KVB];   // [128][32], chunk-swizzled
    __shared__ short P[8][16 * PLD];
    const int t = threadIdx.x;
    const int lane = t & 63;
    const int w = t >> 6;               // 0..7
    const int h = blockIdx.y;
    const int sp = blockIdx.z;
    const int kvh = h >> 2;
    int bx = blockIdx.x;
    const int qt = (bx & 1) ? ((int)gridDim.x - 1 - (bx >> 1)) : (bx >> 1);
    const int qb0 = qt * QB;
    const int lr = lane & 15;
    const int g = lane >> 4;
    const int lk = g * 8;
    const int rowb = qb0 + w * 16 + g * 4;
    const int len = qt + 1;             // equal non-empty splits (nt = 4*(qt+1))
    const int jt0 = sp * len;
    const int jt1 = jt0 + len;

    f32x4 oacc[8] = {};
    f32x4 lacc = {};                           // row-sums via ones-MFMA
    const float scale = 0.08838834764831845f;  // 1/sqrt(128)
    short8 kOnes;
#pragma unroll
    for (int kk = 0; kk < 8; kk++) kOnes[kk] = (short)0x3F80;  // bf16 1.0

    short8 qf[4];
    {
        const short* qp = Qb + (size_t)(qb0 + w * 16 + lr) * HID + h * HD + lk;
#pragma unroll
        for (int kk = 0; kk < 4; kk++)
            qf[kk] = *reinterpret_cast<const short8*>(qp + kk * 32);
    }
    const short* kgb = Kb + (size_t)(kvh * T) * HD;
    const short* vgb = Vt + (size_t)(kvh * HD) * T;
    const int kr4 = lane >> 4;            // K stage: row within 4-row chunk
    const int vr16 = lane >> 2;           // V stage: d-row within 16-row chunk
    const int r7 = ((w & 1) << 2) | kr4;  // (w*4+kr4) & 7
    const int kcol = ((lane & 15) ^ r7) * 8;               // K pre-swizzled col
    const int vcol = ((lane & 3) ^ ((lane >> 2) & 3)) * 8; // V pre-swizzled col

    // prologue: stage tile jt0 into buf 0 (wave w stages chunk w of K and V)
    {
        const int key0 = jt0 * KVB;
        GLOAD16(kgb + (size_t)(key0 + w * 4 + kr4) * HD + kcol, &Ks[0][w * 512]);
        GLOAD16(vgb + (size_t)(w * 16 + vr16) * T + key0 + vcol, &Vs[0][w * 512]);
    }
    __syncthreads();

    int cur = 0;
    for (int j = jt0; j < jt1; j++) {
        const int key0 = j * KVB;
        if (j + 1 < jt1) {
            const int nk0 = key0 + KVB;
            GLOAD16(kgb + (size_t)(nk0 + w * 4 + kr4) * HD + kcol, &Ks[cur ^ 1][w * 512]);
            GLOAD16(vgb + (size_t)(w * 16 + vr16) * T + nk0 + vcol, &Vs[cur ^ 1][w * 512]);
        }
        // ---- QK^T: S[16q][32k] per wave (swizzled K reads) ----
        f32x4 sv[2] = {};
        __builtin_amdgcn_s_setprio(1);
#pragma unroll
        for (int kt = 0; kt < 2; kt++) {
            int r = kt * 16 + lr;
            int rx = (r & 7) * 8;
#pragma unroll
            for (int kk = 0; kk < 4; kk++) {
                short8 b = *reinterpret_cast<const short8*>(
                    &Ks[cur][r * HD + ((kk * 32 + lk) ^ rx)]);
                sv[kt] = __builtin_amdgcn_mfma_f32_16x16x32_bf16(qf[kk], b, sv[kt], 0, 0, 0);
            }
        }
        __builtin_amdgcn_s_setprio(0);
        // ---- fixed-max softmax: p = exp(s*scale - 12), mask -> exp(-inf)=0 ----
        {
            int prow = g * 4;
#pragma unroll
            for (int rr = 0; rr < 4; rr++) {
                int row = rowb + rr;
                float v0 = (key0 + lr <= row) ? fmaf(sv[0][rr], scale, -12.f) : -1e30f;
                float v1 = (key0 + 16 + lr <= row) ? fmaf(sv[1][rr], scale, -12.f) : -1e30f;
                float p0 = __expf(v0);
                float p1 = __expf(v1);
                P[w][(prow + rr) * PLD + lr] = (short)(__float_as_uint(p0) >> 16);
                P[w][(prow + rr) * PLD + 16 + lr] = (short)(__float_as_uint(p1) >> 16);
            }
        }
        // P is wave-private: compiler lgkmcnt ordering suffices, no barrier.
        short8 pa = *reinterpret_cast<const short8*>(&P[w][lr * PLD + lk]);
        // ---- PV: O[16q][128d] += P[16][32] * V[32][128]; l += P.1 ----
        __builtin_amdgcn_s_setprio(1);
        lacc = __builtin_amdgcn_mfma_f32_16x16x32_bf16(pa, kOnes, lacc, 0, 0, 0);
#pragma unroll
        for (int c = 0; c < 8; c++) {
            int r = c * 16 + lr;
            short8 bv = *reinterpret_cast<const short8*>(
                &Vs[cur][r * KVB + ((g ^ (r & 3)) * 8)]);
            oacc[c] = __builtin_amdgcn_mfma_f32_16x16x32_bf16(pa, bv, oacc[c], 0, 0, 0);
        }
        __builtin_amdgcn_s_setprio(0);
        __syncthreads();   // drains staging vmcnt + protects dbuf reuse
        cur ^= 1;
    }
    // ---- emit U: packed u32, permuted cols, NT, full 64B lines ----
    unsigned int* ub = U32 + ((size_t)(sp * NH + h) * T + rowb) * (HD / 2);
#pragma unroll
    for (int cp = 0; cp < 4; cp++)
#pragma unroll
        for (int rr = 0; rr < 4; rr++) {
            unsigned int w32 = (unsigned int)(unsigned short)f2b(oacc[2 * cp][rr]) |
                               ((unsigned int)(unsigned short)f2b(oacc[2 * cp + 1][rr]) << 16);
            __builtin_nontemporal_store(w32, &ub[rr * (HD / 2) + cp * 16 + lr]);
        }
    // ---- stats ----
    if (lr == 0) {
#pragma unroll
        for (int rr = 0; rr < 4; rr++)
            stats[(size_t)(sp * NH + h) * T + rowb + rr] = make_float2(12.f, lacc[rr]);
    }
}

// ------- combine: equal-weight merge of 4 splits (permuted u32 U) -> Ob -------
__global__ __launch_bounds__(256) void combine_kernel(
    const unsigned int* __restrict__ U32, const float2* __restrict__ stats,
    short* __restrict__ Ob) {
    const int w = threadIdx.x >> 6;
    const int lane = threadIdx.x & 63;
    const int rid = blockIdx.x * 4 + w;      // h*T + t
    const int h = rid >> 11;
    const int tt = rid & (T - 1);
    float l[NSPLIT];
    float den = 0.f;
#pragma unroll
    for (int sp = 0; sp < NSPLIT; sp++) {
        l[sp] = stats[(size_t)sp * NH * T + rid].y;
        den += l[sp];
    }
    float inv = 1.0f / den;
    float o0 = 0.f, o1 = 0.f;
#pragma unroll
    for (int sp = 0; sp < NSPLIT; sp++) {
        if (l[sp] > 0.f) {   // wave-uniform branch
            unsigned int u = __builtin_nontemporal_load(
                &U32[((size_t)(sp * NH + h) * T + tt) * (HD / 2) + lane]);
            o0 += b2f((unsigned short)(u & 0xffff));
            o1 += b2f((unsigned short)(u >> 16));
        }
    }
    o0 *= inv; o1 *= inv;
    const int c0 = 32 * (lane >> 4) + (lane & 15);
    short* obp = Ob + (size_t)tt * HID + h * HD;
    obp[c0] = f2b(o0);
    obp[c0 + 16] = f2b(o1);
}

extern "C" void kernel_launch(void* const* d_in, const int* in_sizes, int n_in,
                              void* d_out, int out_size, void* d_ws, size_t ws_size,
                              hipStream_t stream) {
    const float* x = (const float*)d_in[0];
    const int* positions = (const int*)d_in[1];
    const int* qw_q = (const int*)d_in[2];
    const float* sc_q = (const float*)d_in[3];
    const int* qz_q = (const int*)d_in[4];
    const int* qw_k = (const int*)d_in[5];
    const float* sc_k = (const float*)d_in[6];
    const int* qz_k = (const int*)d_in[7];
    const int* qw_v = (const int*)d_in[8];
    const float* sc_v = (const float*)d_in[9];
    const int* qz_v = (const int*)d_in[10];
    const int* qw_o = (const int*)d_in[11];
    const float* sc_o = (const float*)d_in[12];
    const int* qz_o = (const int*)d_in[13];
    const float* qnw = (const float*)d_in[14];
    const float* knw = (const float*)d_in[15];
    float* out = (float*)d_out;

    char* ws = (char*)d_ws;
    short* Wqkv = (short*)(ws);                  // [3072][2048] bf16 (dead after QKV GEMM)
    short* Wo   = (short*)(ws + 12582912);       // [2048][2048] bf16 (live till end)
    short* xb   = (short*)(ws + 20971520);       // [2048][2048] bf16 (dead after QKV GEMM)
    unsigned short* qkvb = (unsigned short*)(ws + 29360128); // [2048][3072] bf16
    short* Qb   = (short*)(ws + 54525952);       // [2048][2048] bf16
    short* Kb   = (short*)(ws + 62914560);       // [4][2048][128] bf16
    short* Vt   = (short*)(ws + 65011712);       // [4][128][2048] bf16
    short* Ob   = (short*)(ws + 67108864);       // [2048][2048] bf16
    float2* stats   = (float2*)(ws);             // [4][16][2048] float2 (over Wqkv)
    unsigned int* U = (unsigned int*)(ws + 20971520); // [4][16][2048][64] u32 = 32 MB

    prep_kernel<<<7168, 256, 0, stream>>>(qw_q, sc_q, qz_q, qw_k, sc_k, qz_k,
                                          qw_v, sc_v, qz_v, qw_o, sc_o, qz_o,
                                          x, Wqkv, Wo, xb);

    dim3 g1(3072 / BN, 2048 / BM);               // 48 x 16 = 768 blocks
    gemm_bt<1><<<g1, 256, 0, stream>>>(xb, Wqkv, (float*)qkvb, 2048, 3072, 2048);

    dim3 g2(1024, 21);
    nrv_kernel<<<g2, 256, 0, stream>>>(qkvb, qnw, knw, positions, Qb, Kb, Vt);

    dim3 g4(T / QB, NH, NSPLIT);                 // 16 x 16 x 4 = 1024 blocks x 512 thr
    attn_split_kernel<<<g4, 512, 0, stream>>>(Qb, Kb, Vt, U, stats);

    combine_kernel<<<(T * NH) / 4, 256, 0, stream>>>(U, stats, Ob);

    dim3 g5(2048 / BN, 2048 / BM);               // 32 x 16 = 512 blocks
    gemm_bt<0><<<g5, 256, 0, stream>>>(Ob, Wo, out, 2048, 2048, 2048);
}